// Round 1
// baseline (942.997 us; speedup 1.0000x reference)
//
#include <hip/hip_runtime.h>
#include <math.h>

#define NB 16
#define NCIN 64
#define NCOUT 64
#define NH 256
#define NW 256
#define NM 64          // 2*M1 row modes
#define NKX 32         // M2 retained columns
#define INV256 (1.0f/256.0f)

// ---------------- Kernel 1: forward partial rfft2 ----------------
// grid = B*CIN blocks, 256 threads. Output xft[b][i][m][kx], m<32 -> ky=m,
// m>=32 -> ky=192+m (i.e. 224..255). Includes ortho norm 1/256.
__global__ __launch_bounds__(256) void fwd_kernel(const float* __restrict__ x,
                                                  float2* __restrict__ xft) {
    __shared__ float2 yw[NH * NKX];       // 64 KiB
    __shared__ float cosT[256];
    __shared__ float sinT[256];
    const int t = threadIdx.x;
    {
        float sv, cv;
        sincosf((2.0f * 3.14159265358979323846f / 256.0f) * (float)t, &sv, &cv);
        cosT[t] = cv; sinT[t] = sv;
    }
    __syncthreads();

    const float4* __restrict__ xp4 =
        (const float4*)(x + (size_t)blockIdx.x * (NH * NW));
    const int kx = t & 31;
    const int hg = t >> 5;                // 0..7

    // Phase 1: Yw[h][kx] = sum_w x[h][w] e^{-2pi i kx w / 256}
    for (int jb = 0; jb < 4; ++jb) {
        float ar[8], ai[8];
        #pragma unroll
        for (int r = 0; r < 8; ++r) { ar[r] = 0.f; ai[r] = 0.f; }
        for (int wq = 0; wq < 64; wq += 2) {
            float4 xv[16];
            #pragma unroll
            for (int q = 0; q < 2; ++q) {
                #pragma unroll
                for (int r = 0; r < 8; ++r) {
                    const int h = hg + 64 * jb + 8 * r;
                    xv[q * 8 + r] = xp4[h * 64 + wq + q];
                }
            }
            #pragma unroll
            for (int q = 0; q < 2; ++q) {
                #pragma unroll
                for (int u = 0; u < 4; ++u) {
                    const int w = (wq + q) * 4 + u;
                    const int tidx = (kx * w) & 255;
                    const float c = cosT[tidx];
                    const float s = sinT[tidx];
                    #pragma unroll
                    for (int r = 0; r < 8; ++r) {
                        const float xvu = (&xv[q * 8 + r].x)[u];
                        ar[r] += xvu * c;
                        ai[r] -= xvu * s;
                    }
                }
            }
        }
        #pragma unroll
        for (int r = 0; r < 8; ++r) {
            const int h = hg + 64 * jb + 8 * r;
            yw[h * NKX + kx] = make_float2(ar[r], ai[r]);
        }
    }
    __syncthreads();

    // Phase 2: xft[m][kx] = (1/256) sum_h Yw[h][kx] e^{-2pi i ky(m) h / 256}
    const int mg = t >> 5;                // 0..7
    float br[8], bi[8];
    #pragma unroll
    for (int j = 0; j < 8; ++j) { br[j] = 0.f; bi[j] = 0.f; }
    for (int h = 0; h < NH; ++h) {
        const float2 yv = yw[h * NKX + kx];
        #pragma unroll
        for (int j = 0; j < 8; ++j) {
            const int m = mg + 8 * j;
            const int ky = (m < 32) ? m : (192 + m);
            const int tidx = (ky * h) & 255;
            const float c = cosT[tidx];
            const float s = sinT[tidx];
            br[j] += yv.x * c + yv.y * s;
            bi[j] += yv.y * c - yv.x * s;
        }
    }
    float2* op = xft + (size_t)blockIdx.x * (NM * NKX);
    #pragma unroll
    for (int j = 0; j < 8; ++j) {
        const int m = mg + 8 * j;
        op[m * NKX + kx] = make_float2(br[j] * INV256, bi[j] * INV256);
    }
}

// ---------------- Kernel 2: per-mode channel contraction ----------------
// grid = (m=64, og=4), 256 threads. oft[b][o][m][kx] = sum_i xft[b][i][m][kx]*w[i][o][m][kx]
__global__ __launch_bounds__(256) void mode_kernel(const float2* __restrict__ xft,
                                                   const int* __restrict__ q1,
                                                   const int* __restrict__ q2,
                                                   const float* __restrict__ w1s,
                                                   const float* __restrict__ w1m,
                                                   const float* __restrict__ w2s,
                                                   const float* __restrict__ w2m,
                                                   float2* __restrict__ oft) {
    __shared__ float2 xs[16 * 33];        // +1 pad: conflict-free
    __shared__ float2 ws[16 * 33];
    const int m = blockIdx.x;             // 0..63
    const int og = blockIdx.y;            // 0..3
    const int t = threadIdx.x;
    const int mm = (m < 32) ? m : (m - 32);
    const int* __restrict__ q = (m < 32) ? q1 : q2;
    const float scale = (m < 32) ? w1s[0] : w2s[0];
    const float wmin  = (m < 32) ? w1m[0] : w2m[0];
    const int b  = t >> 4;                // 0..15
    const int ol = t & 15;                // 0..15

    float accr[32], acci[32];
    #pragma unroll
    for (int k = 0; k < 32; ++k) { accr[k] = 0.f; acci[k] = 0.f; }

    const int2* __restrict__ qp = (const int2*)q;
    for (int i = 0; i < 64; ++i) {
        __syncthreads();
        #pragma unroll
        for (int rep = 0; rep < 2; ++rep) {
            const int idx = t + rep * 256;
            const int bb = idx >> 5, kk = idx & 31;
            xs[bb * 33 + kk] = xft[(size_t)(bb * 64 + i) * (NM * NKX) + m * 32 + kk];
        }
        #pragma unroll
        for (int rep = 0; rep < 2; ++rep) {
            const int idx = t + rep * 256;
            const int oo = idx >> 5, kk = idx & 31;
            const int2 qv = qp[(size_t)(i * 64 + og * 16 + oo) * 1024 + mm * 32 + kk];
            ws[oo * 33 + kk] = make_float2(((float)qv.x + 127.0f) * scale + wmin,
                                           ((float)qv.y + 127.0f) * scale + wmin);
        }
        __syncthreads();
        #pragma unroll
        for (int k = 0; k < 32; ++k) {
            const float2 xv = xs[b * 33 + k];
            const float2 wv = ws[ol * 33 + k];
            accr[k] += xv.x * wv.x - xv.y * wv.y;
            acci[k] += xv.x * wv.y + xv.y * wv.x;
        }
    }
    float2* op = oft + ((size_t)(b * 64 + og * 16 + ol) * NM + m) * NKX;
    #pragma unroll
    for (int k = 0; k < 32; ++k) op[k] = make_float2(accr[k], acci[k]);
}

// ---------------- Kernel 3: inverse partial irfft2 ----------------
// grid = B*COUT blocks, 512 threads.
__global__ __launch_bounds__(512) void inv_kernel(const float2* __restrict__ oft,
                                                  float* __restrict__ out) {
    __shared__ float2 zh[NH * NKX];       // 64 KiB
    __shared__ float2 of[NM * NKX];       // 16 KiB
    __shared__ float cosT[256];
    __shared__ float sinT[256];
    const int t = threadIdx.x;
    if (t < 256) {
        float sv, cv;
        sincosf((2.0f * 3.14159265358979323846f / 256.0f) * (float)t, &sv, &cv);
        cosT[t] = cv; sinT[t] = sv;
    }
    const float2* __restrict__ ip = oft + (size_t)blockIdx.x * (NM * NKX);
    #pragma unroll
    for (int rep = 0; rep < 4; ++rep) of[t + rep * 512] = ip[t + rep * 512];
    __syncthreads();

    // Phase 4: Zh[h][kx] = sum_m of[m][kx] e^{+2pi i ky(m) h / 256}
    {
        const int kx = t & 31;
        const int hg = t >> 5;            // 0..15
        float ar[16], ai[16];
        #pragma unroll
        for (int j = 0; j < 16; ++j) { ar[j] = 0.f; ai[j] = 0.f; }
        for (int mi = 0; mi < NM; ++mi) {
            const float2 ov = of[mi * NKX + kx];
            const int ky = (mi < 32) ? mi : (192 + mi);
            #pragma unroll
            for (int j = 0; j < 16; ++j) {
                const int h = hg * 16 + j;
                const int tidx = (ky * h) & 255;
                const float c = cosT[tidx];
                const float s = sinT[tidx];
                ar[j] += ov.x * c - ov.y * s;
                ai[j] += ov.y * c + ov.x * s;
            }
        }
        #pragma unroll
        for (int j = 0; j < 16; ++j) {
            const int h = hg * 16 + j;
            zh[h * NKX + kx] = make_float2(ar[j], ai[j]);
        }
    }
    __syncthreads();

    // Phase 5: out[h][w] = (1/256)(Re Z[h][0] + 2 sum_{k=1}^{31} Re(Z[h][k] e^{+2pi i k w/256}))
    // fold w and w+128: term_k(w+128) = (-1)^k term_k(w)
    const int w = t & 127;
    const int hh = t >> 7;                // 0..3
    float* __restrict__ op = out + (size_t)blockIdx.x * (NH * NW);
    for (int j = 0; j < 64; ++j) {
        const int h = hh * 64 + j;
        const float2* zrow = &zh[h * NKX];
        float ae = 0.f, ao = 0.f;
        #pragma unroll
        for (int k = 1; k < 32; ++k) {
            const int tidx = (k * w) & 255;
            const float c = cosT[tidx];
            const float s = sinT[tidx];
            const float2 zv = zrow[k];
            const float term = zv.x * c - zv.y * s;
            if (k & 1) ao += term; else ae += term;
        }
        const float z0 = zrow[0].x;
        op[h * NW + w]       = (z0 + 2.f * (ae + ao)) * INV256;
        op[h * NW + w + 128] = (z0 + 2.f * (ae - ao)) * INV256;
    }
}

extern "C" void kernel_launch(void* const* d_in, const int* in_sizes, int n_in,
                              void* d_out, int out_size, void* d_ws, size_t ws_size,
                              hipStream_t stream) {
    const float* x  = (const float*)d_in[0];
    const int* q1   = (const int*)d_in[1];
    const int* q2   = (const int*)d_in[2];
    const float* w1s = (const float*)d_in[3];
    const float* w1m = (const float*)d_in[4];
    const float* w2s = (const float*)d_in[5];
    const float* w2m = (const float*)d_in[6];
    float* out = (float*)d_out;

    float2* xft = (float2*)d_ws;                          // 16 MiB
    float2* oft = xft + (size_t)NB * NCIN * NM * NKX;     // +16 MiB

    fwd_kernel<<<NB * NCIN, 256, 0, stream>>>(x, xft);
    mode_kernel<<<dim3(NM, 4), 256, 0, stream>>>(xft, q1, q2, w1s, w1m, w2s, w2m, oft);
    inv_kernel<<<NB * NCOUT, 512, 0, stream>>>(oft, out);
}

// Round 2
// 602.534 us; speedup vs baseline: 1.5651x; 1.5651x over previous
//
#include <hip/hip_runtime.h>
#include <math.h>

#define NB 16
#define NCIN 64
#define NCOUT 64
#define NH 256
#define NW 256
#define NM 64          // 2*M1 row modes
#define NKX 32         // M2 retained columns
#define INV256 (1.0f/256.0f)

typedef __attribute__((ext_vector_type(8))) short short8v;
typedef __attribute__((ext_vector_type(4))) float f32x4;
typedef unsigned short u16;
typedef unsigned int u32;

// Twiddle fragment tables (ushort offsets within the table region):
//  T1h @ 0      T1l @ 16384   : [kc 8][nt 4][lane 64][e 8]  (phase-1 B frags)
//  C2h @ 32768  C2l @ 49152   : [mt 4][kc 8][lane 64][e 8]  (phase-2 A frags)
//  S2h @ 65536  S2l @ 81920
//  Snh @ 98304  Snl @ 114688
// Total 131072 ushorts = 256 KiB. Lives at the head of the oft region (ws+16MiB);
// only fwd reads it, and mode overwrites that region afterwards.

__device__ __forceinline__ void bf16_split(float v, u16& hi, u16& lo) {
    u32 b = __float_as_uint(v);
    u32 hib = b & 0xffff0000u;
    float lof = v - __uint_as_float(hib);
    hi = (u16)(hib >> 16);
    lo = (u16)(__float_as_uint(lof) >> 16);
}

__global__ __launch_bounds__(256) void init_tw(u16* __restrict__ tw) {
    const int tid = blockIdx.x * 256 + threadIdx.x;   // 0..32767
    const float TWO_PI = 6.28318530717958647692f;
    if (tid < 16384) {
        // T1[w][n]: n=2kx -> cos(th*kx*w), n=2kx+1 -> -sin(th*kx*w)
        const int e = tid & 7, lane = (tid >> 3) & 63;
        const int nt = (tid >> 9) & 3, kc = tid >> 11;
        const int w = kc * 32 + (lane >> 4) * 8 + e;
        const int n = nt * 16 + (lane & 15);
        const int kx = n >> 1, p = n & 1;
        const float ang = TWO_PI * (float)((kx * w) & 255) * INV256;
        const float v = p ? -sinf(ang) : cosf(ang);
        u16 hi, lo; bf16_split(v, hi, lo);
        tw[tid] = hi; tw[16384 + tid] = lo;
    } else {
        const int u = tid - 16384;
        const int e = u & 7, lane = (u >> 3) & 63;
        const int kc = (u >> 9) & 7, mt = u >> 12;
        const int m = mt * 16 + (lane & 15);
        const int h = kc * 32 + (lane >> 4) * 8 + e;
        const int ky = (m < 32) ? m : (192 + m);
        const float ang = TWO_PI * (float)((ky * h) & 255) * INV256;
        const float c = cosf(ang), s = sinf(ang);
        u16 hi, lo;
        bf16_split(c,  hi, lo); tw[32768 + u] = hi; tw[49152 + u]  = lo;
        bf16_split(s,  hi, lo); tw[65536 + u] = hi; tw[81920 + u]  = lo;
        bf16_split(-s, hi, lo); tw[98304 + u] = hi; tw[114688 + u] = lo;
    }
}

// ---------------- Kernel 1: forward partial rfft2 via MFMA ----------------
// grid = B*CIN blocks, 256 threads (4 waves).
// Phase 1: Y[256h][64n] = X[256h][256w] * T1[256w][64n]   (n = 2*kx + re/im)
// Phase 2: Z[64m][32kx](re,im) from 4 real GEMM accumulations over h.
__global__ __launch_bounds__(256) void fwd_mfma(const float* __restrict__ x,
                                                const u16* __restrict__ tw,
                                                float2* __restrict__ xft) {
    // planes: 0=Yr_hi 1=Yr_lo 2=Yi_hi 3=Yi_lo ; each [32 kx][264 h(padded)]
    __shared__ u16 planes[4 * 32 * 264];   // 67584 B
    const int t = threadIdx.x;
    const int lane = t & 63;
    const int wv = t >> 6;            // wave 0..3
    const int l15 = lane & 15;
    const int lk = lane >> 4;         // k-group 0..3
    const float* __restrict__ xb = x + (size_t)blockIdx.x * (NH * NW);

    const u16* __restrict__ T1h = tw;
    const u16* __restrict__ T1l = tw + 16384;

    // ---- Phase 1: wave wv owns h rows [wv*64, wv*64+64) = 4 Mtiles ----
    for (int mt = 0; mt < 4; ++mt) {
        const int hbase = wv * 64 + mt * 16;
        f32x4 acc[4] = {f32x4{0,0,0,0}, f32x4{0,0,0,0}, f32x4{0,0,0,0}, f32x4{0,0,0,0}};
        for (int kc = 0; kc < 8; ++kc) {
            // A frag: X[hbase+l15][kc*32 + lk*8 + 0..7] -> bf16 hi/lo
            const float* xr = xb + (size_t)(hbase + l15) * NW + kc * 32 + lk * 8;
            const float4 xa = *(const float4*)xr;
            const float4 xc = *(const float4*)(xr + 4);
            const float v[8] = {xa.x, xa.y, xa.z, xa.w, xc.x, xc.y, xc.z, xc.w};
            short8v Ah, Al;
            #pragma unroll
            for (int e = 0; e < 8; ++e) {
                u16 hi, lo; bf16_split(v[e], hi, lo);
                Ah[e] = (short)hi; Al[e] = (short)lo;
            }
            const int tbase = (kc * 4) * 512 + lane * 8;
            #pragma unroll
            for (int nt = 0; nt < 4; ++nt) {
                const short8v Bh = *(const short8v*)(T1h + tbase + nt * 512);
                const short8v Bl = *(const short8v*)(T1l + tbase + nt * 512);
                acc[nt] = __builtin_amdgcn_mfma_f32_16x16x32_bf16(Ah, Bh, acc[nt], 0, 0, 0);
                acc[nt] = __builtin_amdgcn_mfma_f32_16x16x32_bf16(Ah, Bl, acc[nt], 0, 0, 0);
                acc[nt] = __builtin_amdgcn_mfma_f32_16x16x32_bf16(Al, Bh, acc[nt], 0, 0, 0);
            }
        }
        // D frags -> LDS planes (transposed: [kx][h]), split bf16 hi/lo.
        #pragma unroll
        for (int nt = 0; nt < 4; ++nt) {
            const int n = nt * 16 + l15;
            const int kx = n >> 1, p = n & 1;
            #pragma unroll
            for (int r = 0; r < 4; ++r) {
                const int h = hbase + lk * 4 + r;
                u16 hi, lo; bf16_split(acc[nt][r], hi, lo);
                planes[(2 * p) * 8448 + kx * 264 + h] = hi;
                planes[(2 * p + 1) * 8448 + kx * 264 + h] = lo;
            }
        }
    }
    __syncthreads();

    // ---- Phase 2: wave wv owns m rows [wv*16, wv*16+16) ----
    const u16* __restrict__ C2h = tw + 32768;
    const u16* __restrict__ C2l = tw + 49152;
    const u16* __restrict__ S2h = tw + 65536;
    const u16* __restrict__ S2l = tw + 81920;
    const u16* __restrict__ Snh = tw + 98304;
    const u16* __restrict__ Snl = tw + 114688;

    f32x4 zre[2] = {f32x4{0,0,0,0}, f32x4{0,0,0,0}};
    f32x4 zim[2] = {f32x4{0,0,0,0}, f32x4{0,0,0,0}};
    for (int kc = 0; kc < 8; ++kc) {
        const int abase = (wv * 8 + kc) * 512 + lane * 8;
        const short8v Ch = *(const short8v*)(C2h + abase);
        const short8v Cl = *(const short8v*)(C2l + abase);
        const short8v Sh = *(const short8v*)(S2h + abase);
        const short8v Sl = *(const short8v*)(S2l + abase);
        const short8v Nh = *(const short8v*)(Snh + abase);
        const short8v Nl = *(const short8v*)(Snl + abase);
        #pragma unroll
        for (int nt = 0; nt < 2; ++nt) {
            const int kx = nt * 16 + l15;
            const int off = kx * 264 + kc * 32 + lk * 8;
            const short8v Yrh = *(const short8v*)(planes + off);
            const short8v Yrl = *(const short8v*)(planes + 8448 + off);
            const short8v Yih = *(const short8v*)(planes + 16896 + off);
            const short8v Yil = *(const short8v*)(planes + 25344 + off);
            // Zre = sum_h C*Yr + S*Yi
            zre[nt] = __builtin_amdgcn_mfma_f32_16x16x32_bf16(Ch, Yrh, zre[nt], 0, 0, 0);
            zre[nt] = __builtin_amdgcn_mfma_f32_16x16x32_bf16(Ch, Yrl, zre[nt], 0, 0, 0);
            zre[nt] = __builtin_amdgcn_mfma_f32_16x16x32_bf16(Cl, Yrh, zre[nt], 0, 0, 0);
            zre[nt] = __builtin_amdgcn_mfma_f32_16x16x32_bf16(Sh, Yih, zre[nt], 0, 0, 0);
            zre[nt] = __builtin_amdgcn_mfma_f32_16x16x32_bf16(Sh, Yil, zre[nt], 0, 0, 0);
            zre[nt] = __builtin_amdgcn_mfma_f32_16x16x32_bf16(Sl, Yih, zre[nt], 0, 0, 0);
            // Zim = sum_h C*Yi - S*Yr
            zim[nt] = __builtin_amdgcn_mfma_f32_16x16x32_bf16(Ch, Yih, zim[nt], 0, 0, 0);
            zim[nt] = __builtin_amdgcn_mfma_f32_16x16x32_bf16(Ch, Yil, zim[nt], 0, 0, 0);
            zim[nt] = __builtin_amdgcn_mfma_f32_16x16x32_bf16(Cl, Yih, zim[nt], 0, 0, 0);
            zim[nt] = __builtin_amdgcn_mfma_f32_16x16x32_bf16(Nh, Yrh, zim[nt], 0, 0, 0);
            zim[nt] = __builtin_amdgcn_mfma_f32_16x16x32_bf16(Nh, Yrl, zim[nt], 0, 0, 0);
            zim[nt] = __builtin_amdgcn_mfma_f32_16x16x32_bf16(Nl, Yrh, zim[nt], 0, 0, 0);
        }
    }
    float2* __restrict__ op = xft + (size_t)blockIdx.x * (NM * NKX);
    #pragma unroll
    for (int nt = 0; nt < 2; ++nt) {
        const int kx = nt * 16 + l15;
        #pragma unroll
        for (int r = 0; r < 4; ++r) {
            const int m = wv * 16 + lk * 4 + r;
            op[m * NKX + kx] = make_float2(zre[nt][r] * INV256, zim[nt][r] * INV256);
        }
    }
}

// ---------------- Kernel 2: per-mode channel contraction ----------------
__global__ __launch_bounds__(256) void mode_kernel(const float2* __restrict__ xft,
                                                   const int* __restrict__ q1,
                                                   const int* __restrict__ q2,
                                                   const float* __restrict__ w1s,
                                                   const float* __restrict__ w1m,
                                                   const float* __restrict__ w2s,
                                                   const float* __restrict__ w2m,
                                                   float2* __restrict__ oft) {
    __shared__ float2 xs[16 * 33];
    __shared__ float2 ws[16 * 33];
    const int m = blockIdx.x;
    const int og = blockIdx.y;
    const int t = threadIdx.x;
    const int mm = (m < 32) ? m : (m - 32);
    const int* __restrict__ q = (m < 32) ? q1 : q2;
    const float scale = (m < 32) ? w1s[0] : w2s[0];
    const float wmin  = (m < 32) ? w1m[0] : w2m[0];
    const int b  = t >> 4;
    const int ol = t & 15;

    float accr[32], acci[32];
    #pragma unroll
    for (int k = 0; k < 32; ++k) { accr[k] = 0.f; acci[k] = 0.f; }

    const int2* __restrict__ qp = (const int2*)q;
    for (int i = 0; i < 64; ++i) {
        __syncthreads();
        #pragma unroll
        for (int rep = 0; rep < 2; ++rep) {
            const int idx = t + rep * 256;
            const int bb = idx >> 5, kk = idx & 31;
            xs[bb * 33 + kk] = xft[(size_t)(bb * 64 + i) * (NM * NKX) + m * 32 + kk];
        }
        #pragma unroll
        for (int rep = 0; rep < 2; ++rep) {
            const int idx = t + rep * 256;
            const int oo = idx >> 5, kk = idx & 31;
            const int2 qv = qp[(size_t)(i * 64 + og * 16 + oo) * 1024 + mm * 32 + kk];
            ws[oo * 33 + kk] = make_float2(((float)qv.x + 127.0f) * scale + wmin,
                                           ((float)qv.y + 127.0f) * scale + wmin);
        }
        __syncthreads();
        #pragma unroll
        for (int k = 0; k < 32; ++k) {
            const float2 xv = xs[b * 33 + k];
            const float2 wv = ws[ol * 33 + k];
            accr[k] += xv.x * wv.x - xv.y * wv.y;
            acci[k] += xv.x * wv.y + xv.y * wv.x;
        }
    }
    float2* op = oft + ((size_t)(b * 64 + og * 16 + ol) * NM + m) * NKX;
    #pragma unroll
    for (int k = 0; k < 32; ++k) op[k] = make_float2(accr[k], acci[k]);
}

// ---------------- Kernel 3: inverse partial irfft2 ----------------
__global__ __launch_bounds__(512) void inv_kernel(const float2* __restrict__ oft,
                                                  float* __restrict__ out) {
    __shared__ float2 zh[NH * NKX];
    __shared__ float2 of[NM * NKX];
    __shared__ float cosT[256];
    __shared__ float sinT[256];
    const int t = threadIdx.x;
    if (t < 256) {
        float sv, cv;
        sincosf((2.0f * 3.14159265358979323846f / 256.0f) * (float)t, &sv, &cv);
        cosT[t] = cv; sinT[t] = sv;
    }
    const float2* __restrict__ ip = oft + (size_t)blockIdx.x * (NM * NKX);
    #pragma unroll
    for (int rep = 0; rep < 4; ++rep) of[t + rep * 512] = ip[t + rep * 512];
    __syncthreads();

    {
        const int kx = t & 31;
        const int hg = t >> 5;
        float ar[16], ai[16];
        #pragma unroll
        for (int j = 0; j < 16; ++j) { ar[j] = 0.f; ai[j] = 0.f; }
        for (int mi = 0; mi < NM; ++mi) {
            const float2 ov = of[mi * NKX + kx];
            const int ky = (mi < 32) ? mi : (192 + mi);
            #pragma unroll
            for (int j = 0; j < 16; ++j) {
                const int h = hg * 16 + j;
                const int tidx = (ky * h) & 255;
                const float c = cosT[tidx];
                const float s = sinT[tidx];
                ar[j] += ov.x * c - ov.y * s;
                ai[j] += ov.y * c + ov.x * s;
            }
        }
        #pragma unroll
        for (int j = 0; j < 16; ++j) {
            const int h = hg * 16 + j;
            zh[h * NKX + kx] = make_float2(ar[j], ai[j]);
        }
    }
    __syncthreads();

    const int w = t & 127;
    const int hh = t >> 7;
    float* __restrict__ op = out + (size_t)blockIdx.x * (NH * NW);
    for (int j = 0; j < 64; ++j) {
        const int h = hh * 64 + j;
        const float2* zrow = &zh[h * NKX];
        float ae = 0.f, ao = 0.f;
        #pragma unroll
        for (int k = 1; k < 32; ++k) {
            const int tidx = (k * w) & 255;
            const float c = cosT[tidx];
            const float s = sinT[tidx];
            const float2 zv = zrow[k];
            const float term = zv.x * c - zv.y * s;
            if (k & 1) ao += term; else ae += term;
        }
        const float z0 = zrow[0].x;
        op[h * NW + w]       = (z0 + 2.f * (ae + ao)) * INV256;
        op[h * NW + w + 128] = (z0 + 2.f * (ae - ao)) * INV256;
    }
}

extern "C" void kernel_launch(void* const* d_in, const int* in_sizes, int n_in,
                              void* d_out, int out_size, void* d_ws, size_t ws_size,
                              hipStream_t stream) {
    const float* x  = (const float*)d_in[0];
    const int* q1   = (const int*)d_in[1];
    const int* q2   = (const int*)d_in[2];
    const float* w1s = (const float*)d_in[3];
    const float* w1m = (const float*)d_in[4];
    const float* w2s = (const float*)d_in[5];
    const float* w2m = (const float*)d_in[6];
    float* out = (float*)d_out;

    float2* xft = (float2*)d_ws;                          // 16 MiB
    float2* oft = xft + (size_t)NB * NCIN * NM * NKX;     // +16 MiB
    u16* tw = (u16*)oft;  // twiddle frag tables live at the head of the oft
                          // region: used only by fwd, then clobbered by mode.

    init_tw<<<128, 256, 0, stream>>>(tw);
    fwd_mfma<<<NB * NCIN, 256, 0, stream>>>(x, tw, xft);
    mode_kernel<<<dim3(NM, 4), 256, 0, stream>>>(xft, q1, q2, w1s, w1m, w2s, w2m, oft);
    inv_kernel<<<NB * NCOUT, 512, 0, stream>>>(oft, out);
}

// Round 3
// 337.949 us; speedup vs baseline: 2.7904x; 1.7829x over previous
//
#include <hip/hip_runtime.h>
#include <math.h>

#define NB 16
#define NCIN 64
#define NCOUT 64
#define NH 256
#define NW 256
#define NM 64          // 2*M1 row modes
#define NKX 32         // M2 retained columns
#define INV256 (1.0f/256.0f)

typedef __attribute__((ext_vector_type(8))) short short8v;
typedef __attribute__((ext_vector_type(4))) float f32x4;
typedef unsigned short u16;
typedef unsigned int u32;

__device__ __forceinline__ void bf16_split(float v, u16& hi, u16& lo) {
    u32 b = __float_as_uint(v);
    u32 hib = b & 0xffff0000u;
    float lof = v - __uint_as_float(hib);
    hi = (u16)(hib >> 16);
    lo = (u16)(__float_as_uint(lof) >> 16);
}

__device__ __forceinline__ u16 bf16_rtn(float v) {
    u32 b = __float_as_uint(v);
    u32 r = b + 0x7fffu + ((b >> 16) & 1u);
    return (u16)(r >> 16);
}

// ---------------- fwd twiddle tables (at head of oft region) ----------------
//  T1h @ 0      T1l @ 16384   : [kc 8][nt 4][lane 64][e 8]  (phase-1 B frags)
//  C2h @ 32768  C2l @ 49152   : [mt 4][kc 8][lane 64][e 8]  (phase-2 A frags)
//  S2h @ 65536  S2l @ 81920
//  Snh @ 98304  Snl @ 114688
__global__ __launch_bounds__(256) void init_tw(u16* __restrict__ tw) {
    const int tid = blockIdx.x * 256 + threadIdx.x;   // 0..32767
    const float TWO_PI = 6.28318530717958647692f;
    if (tid < 16384) {
        const int e = tid & 7, lane = (tid >> 3) & 63;
        const int nt = (tid >> 9) & 3, kc = tid >> 11;
        const int w = kc * 32 + (lane >> 4) * 8 + e;
        const int n = nt * 16 + (lane & 15);
        const int kx = n >> 1, p = n & 1;
        const float ang = TWO_PI * (float)((kx * w) & 255) * INV256;
        const float v = p ? -sinf(ang) : cosf(ang);
        u16 hi, lo; bf16_split(v, hi, lo);
        tw[tid] = hi; tw[16384 + tid] = lo;
    } else {
        const int u = tid - 16384;
        const int e = u & 7, lane = (u >> 3) & 63;
        const int kc = (u >> 9) & 7, mt = u >> 12;
        const int m = mt * 16 + (lane & 15);
        const int h = kc * 32 + (lane >> 4) * 8 + e;
        const int ky = (m < 32) ? m : (192 + m);
        const float ang = TWO_PI * (float)((ky * h) & 255) * INV256;
        const float c = cosf(ang), s = sinf(ang);
        u16 hi, lo;
        bf16_split(c,  hi, lo); tw[32768 + u] = hi; tw[49152 + u]  = lo;
        bf16_split(s,  hi, lo); tw[65536 + u] = hi; tw[81920 + u]  = lo;
        bf16_split(-s, hi, lo); tw[98304 + u] = hi; tw[114688 + u] = lo;
    }
}

// ---------------- inv twiddle tables (written into dead xft region) ---------
//  C4 @ 0      S4 @ 16384    N4 @ 32768 : [HT 16][kc 2][lane 64][e 8]
//  W5 @ 49152                           : [nt 16][kc 2][lane 64][e 8]
//  W5 k-order interleaved: kk = 2*kx + c; c=0 -> wt*cos/256, c=1 -> -wt*sin/256
__global__ __launch_bounds__(256) void init_tw2(u16* __restrict__ tw2) {
    const int tid = blockIdx.x * 256 + threadIdx.x;   // 0..32767
    const float TWO_PI = 6.28318530717958647692f;
    if (tid < 16384) {
        const int e = tid & 7, lane = (tid >> 3) & 63;
        const int kc = (tid >> 9) & 1, HT = tid >> 10;
        const int h = HT * 16 + (lane & 15);
        const int m = kc * 32 + ((lane >> 4) << 3) + e;
        const int ky = (m < 32) ? m : (192 + m);
        const float ang = TWO_PI * (float)((ky * h) & 255) * INV256;
        tw2[tid]         = bf16_rtn(cosf(ang));
        tw2[16384 + tid] = bf16_rtn(sinf(ang));
        tw2[32768 + tid] = bf16_rtn(-sinf(ang));
    } else {
        const int u = tid - 16384;
        const int e = u & 7, lane = (u >> 3) & 63;
        const int kc = (u >> 9) & 1, nt = u >> 10;
        const int w = nt * 16 + (lane & 15);
        const int kk = kc * 32 + ((lane >> 4) << 3) + e;
        const int kx = kk >> 1, c = kk & 1;
        const float wt = (kx == 0) ? 1.f : 2.f;
        const float ang = TWO_PI * (float)((kx * w) & 255) * INV256;
        const float v = c ? (-wt * sinf(ang) * INV256) : (wt * cosf(ang) * INV256);
        tw2[49152 + u] = bf16_rtn(v);
    }
}

// ---------------- Kernel 1: forward partial rfft2 via MFMA ----------------
__global__ __launch_bounds__(256) void fwd_mfma(const float* __restrict__ x,
                                                const u16* __restrict__ tw,
                                                float2* __restrict__ xft) {
    __shared__ u16 planes[4 * 32 * 264];   // 67584 B
    const int t = threadIdx.x;
    const int lane = t & 63;
    const int wv = t >> 6;
    const int l15 = lane & 15;
    const int lk = lane >> 4;
    const float* __restrict__ xb = x + (size_t)blockIdx.x * (NH * NW);

    const u16* __restrict__ T1h = tw;
    const u16* __restrict__ T1l = tw + 16384;

    for (int mt = 0; mt < 4; ++mt) {
        const int hbase = wv * 64 + mt * 16;
        f32x4 acc[4] = {f32x4{0,0,0,0}, f32x4{0,0,0,0}, f32x4{0,0,0,0}, f32x4{0,0,0,0}};
        for (int kc = 0; kc < 8; ++kc) {
            const float* xr = xb + (size_t)(hbase + l15) * NW + kc * 32 + lk * 8;
            const float4 xa = *(const float4*)xr;
            const float4 xc = *(const float4*)(xr + 4);
            const float v[8] = {xa.x, xa.y, xa.z, xa.w, xc.x, xc.y, xc.z, xc.w};
            short8v Ah, Al;
            #pragma unroll
            for (int e = 0; e < 8; ++e) {
                u16 hi, lo; bf16_split(v[e], hi, lo);
                Ah[e] = (short)hi; Al[e] = (short)lo;
            }
            const int tbase = (kc * 4) * 512 + lane * 8;
            #pragma unroll
            for (int nt = 0; nt < 4; ++nt) {
                const short8v Bh = *(const short8v*)(T1h + tbase + nt * 512);
                const short8v Bl = *(const short8v*)(T1l + tbase + nt * 512);
                acc[nt] = __builtin_amdgcn_mfma_f32_16x16x32_bf16(Ah, Bh, acc[nt], 0, 0, 0);
                acc[nt] = __builtin_amdgcn_mfma_f32_16x16x32_bf16(Ah, Bl, acc[nt], 0, 0, 0);
                acc[nt] = __builtin_amdgcn_mfma_f32_16x16x32_bf16(Al, Bh, acc[nt], 0, 0, 0);
            }
        }
        #pragma unroll
        for (int nt = 0; nt < 4; ++nt) {
            const int n = nt * 16 + l15;
            const int kx = n >> 1, p = n & 1;
            #pragma unroll
            for (int r = 0; r < 4; ++r) {
                const int h = hbase + lk * 4 + r;
                u16 hi, lo; bf16_split(acc[nt][r], hi, lo);
                planes[(2 * p) * 8448 + kx * 264 + h] = hi;
                planes[(2 * p + 1) * 8448 + kx * 264 + h] = lo;
            }
        }
    }
    __syncthreads();

    const u16* __restrict__ C2h = tw + 32768;
    const u16* __restrict__ C2l = tw + 49152;
    const u16* __restrict__ S2h = tw + 65536;
    const u16* __restrict__ S2l = tw + 81920;
    const u16* __restrict__ Snh = tw + 98304;
    const u16* __restrict__ Snl = tw + 114688;

    f32x4 zre[2] = {f32x4{0,0,0,0}, f32x4{0,0,0,0}};
    f32x4 zim[2] = {f32x4{0,0,0,0}, f32x4{0,0,0,0}};
    for (int kc = 0; kc < 8; ++kc) {
        const int abase = (wv * 8 + kc) * 512 + lane * 8;
        const short8v Ch = *(const short8v*)(C2h + abase);
        const short8v Cl = *(const short8v*)(C2l + abase);
        const short8v Sh = *(const short8v*)(S2h + abase);
        const short8v Sl = *(const short8v*)(S2l + abase);
        const short8v Nh = *(const short8v*)(Snh + abase);
        const short8v Nl = *(const short8v*)(Snl + abase);
        #pragma unroll
        for (int nt = 0; nt < 2; ++nt) {
            const int kx = nt * 16 + l15;
            const int off = kx * 264 + kc * 32 + lk * 8;
            const short8v Yrh = *(const short8v*)(planes + off);
            const short8v Yrl = *(const short8v*)(planes + 8448 + off);
            const short8v Yih = *(const short8v*)(planes + 16896 + off);
            const short8v Yil = *(const short8v*)(planes + 25344 + off);
            zre[nt] = __builtin_amdgcn_mfma_f32_16x16x32_bf16(Ch, Yrh, zre[nt], 0, 0, 0);
            zre[nt] = __builtin_amdgcn_mfma_f32_16x16x32_bf16(Ch, Yrl, zre[nt], 0, 0, 0);
            zre[nt] = __builtin_amdgcn_mfma_f32_16x16x32_bf16(Cl, Yrh, zre[nt], 0, 0, 0);
            zre[nt] = __builtin_amdgcn_mfma_f32_16x16x32_bf16(Sh, Yih, zre[nt], 0, 0, 0);
            zre[nt] = __builtin_amdgcn_mfma_f32_16x16x32_bf16(Sh, Yil, zre[nt], 0, 0, 0);
            zre[nt] = __builtin_amdgcn_mfma_f32_16x16x32_bf16(Sl, Yih, zre[nt], 0, 0, 0);
            zim[nt] = __builtin_amdgcn_mfma_f32_16x16x32_bf16(Ch, Yih, zim[nt], 0, 0, 0);
            zim[nt] = __builtin_amdgcn_mfma_f32_16x16x32_bf16(Ch, Yil, zim[nt], 0, 0, 0);
            zim[nt] = __builtin_amdgcn_mfma_f32_16x16x32_bf16(Cl, Yih, zim[nt], 0, 0, 0);
            zim[nt] = __builtin_amdgcn_mfma_f32_16x16x32_bf16(Nh, Yrh, zim[nt], 0, 0, 0);
            zim[nt] = __builtin_amdgcn_mfma_f32_16x16x32_bf16(Nh, Yrl, zim[nt], 0, 0, 0);
            zim[nt] = __builtin_amdgcn_mfma_f32_16x16x32_bf16(Nl, Yrh, zim[nt], 0, 0, 0);
        }
    }
    float2* __restrict__ op = xft + (size_t)blockIdx.x * (NM * NKX);
    #pragma unroll
    for (int nt = 0; nt < 2; ++nt) {
        const int kx = nt * 16 + l15;
        #pragma unroll
        for (int r = 0; r < 4; ++r) {
            const int m = wv * 16 + lk * 4 + r;
            op[m * NKX + kx] = make_float2(zre[nt][r] * INV256, zim[nt][r] * INV256);
        }
    }
}

// ---------------- Kernel 2: per-mode channel contraction ----------------
__global__ __launch_bounds__(256) void mode_kernel(const float2* __restrict__ xft,
                                                   const int* __restrict__ q1,
                                                   const int* __restrict__ q2,
                                                   const float* __restrict__ w1s,
                                                   const float* __restrict__ w1m,
                                                   const float* __restrict__ w2s,
                                                   const float* __restrict__ w2m,
                                                   float2* __restrict__ oft) {
    __shared__ float2 xs[16 * 33];
    __shared__ float2 ws[16 * 33];
    const int m = blockIdx.x;
    const int og = blockIdx.y;
    const int t = threadIdx.x;
    const int mm = (m < 32) ? m : (m - 32);
    const int* __restrict__ q = (m < 32) ? q1 : q2;
    const float scale = (m < 32) ? w1s[0] : w2s[0];
    const float wmin  = (m < 32) ? w1m[0] : w2m[0];
    const int b  = t >> 4;
    const int ol = t & 15;

    float accr[32], acci[32];
    #pragma unroll
    for (int k = 0; k < 32; ++k) { accr[k] = 0.f; acci[k] = 0.f; }

    const int2* __restrict__ qp = (const int2*)q;
    for (int i = 0; i < 64; ++i) {
        __syncthreads();
        #pragma unroll
        for (int rep = 0; rep < 2; ++rep) {
            const int idx = t + rep * 256;
            const int bb = idx >> 5, kk = idx & 31;
            xs[bb * 33 + kk] = xft[(size_t)(bb * 64 + i) * (NM * NKX) + m * 32 + kk];
        }
        #pragma unroll
        for (int rep = 0; rep < 2; ++rep) {
            const int idx = t + rep * 256;
            const int oo = idx >> 5, kk = idx & 31;
            const int2 qv = qp[(size_t)(i * 64 + og * 16 + oo) * 1024 + mm * 32 + kk];
            ws[oo * 33 + kk] = make_float2(((float)qv.x + 127.0f) * scale + wmin,
                                           ((float)qv.y + 127.0f) * scale + wmin);
        }
        __syncthreads();
        #pragma unroll
        for (int k = 0; k < 32; ++k) {
            const float2 xv = xs[b * 33 + k];
            const float2 wv = ws[ol * 33 + k];
            accr[k] += xv.x * wv.x - xv.y * wv.y;
            acci[k] += xv.x * wv.y + xv.y * wv.x;
        }
    }
    float2* op = oft + ((size_t)(b * 64 + og * 16 + ol) * NM + m) * NKX;
    #pragma unroll
    for (int k = 0; k < 32; ++k) op[k] = make_float2(accr[k], acci[k]);
}

// ---------------- Kernel 3: inverse partial irfft2 via MFMA ----------------
// grid = B*COUT = 1024 blocks, 256 threads (4 waves).
// Phase 4: Z[256h][32kx](re,im) = twiddle[h][m] x O[m][kx]   (K=64)
// Phase 5: out[256h][256w] = Zstack[256h][64kk] x W5[64kk][256w]
// LDS (ushort): OrP @0 [32kx][72], OiP @2304 [32kx][72],
//               Zp @4608 [256h][72] with kk = 2*kx + (0:re,1:im)
__global__ __launch_bounds__(256) void inv_mfma(const float2* __restrict__ oft,
                                                const u16* __restrict__ tw2,
                                                float* __restrict__ out) {
    __shared__ u16 lds[23040];   // 46080 B
    const int t = threadIdx.x;
    const int lane = t & 63;
    const int wv = t >> 6;
    const int l15 = lane & 15;
    const int lk = lane >> 4;

    const float2* __restrict__ ip = oft + (size_t)blockIdx.x * (NM * NKX);
    #pragma unroll
    for (int r = 0; r < 8; ++r) {
        const int idx = r * 256 + t;
        const int m = idx >> 5, kx = idx & 31;
        const float2 v = ip[idx];
        lds[kx * 72 + m]        = bf16_rtn(v.x);
        lds[2304 + kx * 72 + m] = bf16_rtn(v.y);
    }
    __syncthreads();

    const u16* __restrict__ C4 = tw2;
    const u16* __restrict__ S4 = tw2 + 16384;
    const u16* __restrict__ N4 = tw2 + 32768;

    // B-frags from staged of-planes (reused across all 4 h-tiles of this wave)
    short8v Br[2][2], Bi[2][2];
    #pragma unroll
    for (int nt = 0; nt < 2; ++nt) {
        #pragma unroll
        for (int kc = 0; kc < 2; ++kc) {
            const int off = (nt * 16 + l15) * 72 + kc * 32 + lk * 8;
            Br[nt][kc] = *(const short8v*)(lds + off);
            Bi[nt][kc] = *(const short8v*)(lds + 2304 + off);
        }
    }

    for (int mt = 0; mt < 4; ++mt) {
        const int HT = wv * 4 + mt;
        f32x4 zr[2] = {f32x4{0,0,0,0}, f32x4{0,0,0,0}};
        f32x4 zi[2] = {f32x4{0,0,0,0}, f32x4{0,0,0,0}};
        #pragma unroll
        for (int kc = 0; kc < 2; ++kc) {
            const int abase = ((HT * 2 + kc) * 64 + lane) * 8;
            const short8v C = *(const short8v*)(C4 + abase);
            const short8v S = *(const short8v*)(S4 + abase);
            const short8v N = *(const short8v*)(N4 + abase);
            #pragma unroll
            for (int nt = 0; nt < 2; ++nt) {
                zr[nt] = __builtin_amdgcn_mfma_f32_16x16x32_bf16(C, Br[nt][kc], zr[nt], 0, 0, 0);
                zr[nt] = __builtin_amdgcn_mfma_f32_16x16x32_bf16(N, Bi[nt][kc], zr[nt], 0, 0, 0);
                zi[nt] = __builtin_amdgcn_mfma_f32_16x16x32_bf16(S, Br[nt][kc], zi[nt], 0, 0, 0);
                zi[nt] = __builtin_amdgcn_mfma_f32_16x16x32_bf16(C, Bi[nt][kc], zi[nt], 0, 0, 0);
            }
        }
        // D -> Zp, (Zr,Zi) packed per kx as one u32 write
        #pragma unroll
        for (int nt = 0; nt < 2; ++nt) {
            const int kx = nt * 16 + l15;
            #pragma unroll
            for (int r = 0; r < 4; ++r) {
                const int h = HT * 16 + lk * 4 + r;
                const u32 pk = (u32)bf16_rtn(zr[nt][r]) | ((u32)bf16_rtn(zi[nt][r]) << 16);
                *(u32*)(lds + 4608 + h * 72 + 2 * kx) = pk;
            }
        }
    }
    __syncthreads();

    const u16* __restrict__ W5 = tw2 + 49152;
    float* __restrict__ op = out + (size_t)blockIdx.x * (NH * NW);
    for (int nt = 0; nt < 16; ++nt) {
        const short8v B0 = *(const short8v*)(W5 + ((nt * 2 + 0) * 64 + lane) * 8);
        const short8v B1 = *(const short8v*)(W5 + ((nt * 2 + 1) * 64 + lane) * 8);
        const int w = nt * 16 + l15;
        #pragma unroll
        for (int mt = 0; mt < 4; ++mt) {
            const int HT = wv * 4 + mt;
            const int h0 = HT * 16 + l15;
            const short8v A0 = *(const short8v*)(lds + 4608 + h0 * 72 + lk * 8);
            const short8v A1 = *(const short8v*)(lds + 4608 + h0 * 72 + 32 + lk * 8);
            f32x4 acc = {0, 0, 0, 0};
            acc = __builtin_amdgcn_mfma_f32_16x16x32_bf16(A0, B0, acc, 0, 0, 0);
            acc = __builtin_amdgcn_mfma_f32_16x16x32_bf16(A1, B1, acc, 0, 0, 0);
            #pragma unroll
            for (int r = 0; r < 4; ++r) {
                const int h = HT * 16 + lk * 4 + r;
                op[h * 256 + w] = acc[r];
            }
        }
    }
}

extern "C" void kernel_launch(void* const* d_in, const int* in_sizes, int n_in,
                              void* d_out, int out_size, void* d_ws, size_t ws_size,
                              hipStream_t stream) {
    const float* x  = (const float*)d_in[0];
    const int* q1   = (const int*)d_in[1];
    const int* q2   = (const int*)d_in[2];
    const float* w1s = (const float*)d_in[3];
    const float* w1m = (const float*)d_in[4];
    const float* w2s = (const float*)d_in[5];
    const float* w2m = (const float*)d_in[6];
    float* out = (float*)d_out;

    float2* xft = (float2*)d_ws;                          // 16 MiB
    float2* oft = xft + (size_t)NB * NCIN * NM * NKX;     // +16 MiB
    u16* tw  = (u16*)oft;   // fwd tables: head of oft region, clobbered by mode
    u16* tw2 = (u16*)xft;   // inv tables: head of xft region, written after mode

    init_tw<<<128, 256, 0, stream>>>(tw);
    fwd_mfma<<<NB * NCIN, 256, 0, stream>>>(x, tw, xft);
    mode_kernel<<<dim3(NM, 4), 256, 0, stream>>>(xft, q1, q2, w1s, w1m, w2s, w2m, oft);
    init_tw2<<<128, 256, 0, stream>>>(tw2);
    inv_mfma<<<NB * NCOUT, 256, 0, stream>>>(oft, tw2, out);
}

// Round 4
// 223.677 us; speedup vs baseline: 4.2159x; 1.5109x over previous
//
#include <hip/hip_runtime.h>
#include <math.h>

#define NB 16
#define NCIN 64
#define NCOUT 64
#define NH 256
#define NW 256
#define NM 64          // 2*M1 row modes
#define NKX 32         // M2 retained columns
#define INV256 (1.0f/256.0f)

typedef __attribute__((ext_vector_type(8))) short short8v;
typedef __attribute__((ext_vector_type(4))) float f32x4;
typedef unsigned short u16;
typedef unsigned int u32;

__device__ __forceinline__ void bf16_split(float v, u16& hi, u16& lo) {
    u32 b = __float_as_uint(v);
    u32 hib = b & 0xffff0000u;
    float lof = v - __uint_as_float(hib);
    hi = (u16)(hib >> 16);
    lo = (u16)(__float_as_uint(lof) >> 16);
}

__device__ __forceinline__ u16 bf16_rtn(float v) {
    u32 b = __float_as_uint(v);
    u32 r = b + 0x7fffu + ((b >> 16) & 1u);
    return (u16)(r >> 16);
}

// ---------------- fwd twiddle tables (at head of oft region) ----------------
//  T1h @ 0      T1l @ 16384   : [kc 8][nt 4][lane 64][e 8]  (phase-1 B frags)
//  C2h @ 32768  C2l @ 49152   : [mt 4][kc 8][lane 64][e 8]  (phase-2 A frags)
//  S2h @ 65536  S2l @ 81920
//  Snh @ 98304  Snl @ 114688
__global__ __launch_bounds__(256) void init_tw(u16* __restrict__ tw) {
    const int tid = blockIdx.x * 256 + threadIdx.x;   // 0..32767
    const float TWO_PI = 6.28318530717958647692f;
    if (tid < 16384) {
        const int e = tid & 7, lane = (tid >> 3) & 63;
        const int nt = (tid >> 9) & 3, kc = tid >> 11;
        const int w = kc * 32 + (lane >> 4) * 8 + e;
        const int n = nt * 16 + (lane & 15);
        const int kx = n >> 1, p = n & 1;
        const float ang = TWO_PI * (float)((kx * w) & 255) * INV256;
        const float v = p ? -sinf(ang) : cosf(ang);
        u16 hi, lo; bf16_split(v, hi, lo);
        tw[tid] = hi; tw[16384 + tid] = lo;
    } else {
        const int u = tid - 16384;
        const int e = u & 7, lane = (u >> 3) & 63;
        const int kc = (u >> 9) & 7, mt = u >> 12;
        const int m = mt * 16 + (lane & 15);
        const int h = kc * 32 + (lane >> 4) * 8 + e;
        const int ky = (m < 32) ? m : (192 + m);
        const float ang = TWO_PI * (float)((ky * h) & 255) * INV256;
        const float c = cosf(ang), s = sinf(ang);
        u16 hi, lo;
        bf16_split(c,  hi, lo); tw[32768 + u] = hi; tw[49152 + u]  = lo;
        bf16_split(s,  hi, lo); tw[65536 + u] = hi; tw[81920 + u]  = lo;
        bf16_split(-s, hi, lo); tw[98304 + u] = hi; tw[114688 + u] = lo;
    }
}

// ---------------- inv twiddle tables (written into dead xft region) ---------
//  C4 @ 0      S4 @ 16384    N4 @ 32768 : [HT 16][kc 2][lane 64][e 8]
//  W5 @ 49152                           : [nt 16][kc 2][lane 64][e 8]
//  W5 k-order interleaved: kk = 2*kx + c; c=0 -> wt*cos/256, c=1 -> -wt*sin/256
__global__ __launch_bounds__(256) void init_tw2(u16* __restrict__ tw2) {
    const int tid = blockIdx.x * 256 + threadIdx.x;   // 0..32767
    const float TWO_PI = 6.28318530717958647692f;
    if (tid < 16384) {
        const int e = tid & 7, lane = (tid >> 3) & 63;
        const int kc = (tid >> 9) & 1, HT = tid >> 10;
        const int h = HT * 16 + (lane & 15);
        const int m = kc * 32 + ((lane >> 4) << 3) + e;
        const int ky = (m < 32) ? m : (192 + m);
        const float ang = TWO_PI * (float)((ky * h) & 255) * INV256;
        tw2[tid]         = bf16_rtn(cosf(ang));
        tw2[16384 + tid] = bf16_rtn(sinf(ang));
        tw2[32768 + tid] = bf16_rtn(-sinf(ang));
    } else {
        const int u = tid - 16384;
        const int e = u & 7, lane = (u >> 3) & 63;
        const int kc = (u >> 9) & 1, nt = u >> 10;
        const int w = nt * 16 + (lane & 15);
        const int kk = kc * 32 + ((lane >> 4) << 3) + e;
        const int kx = kk >> 1, c = kk & 1;
        const float wt = (kx == 0) ? 1.f : 2.f;
        const float ang = TWO_PI * (float)((kx * w) & 255) * INV256;
        const float v = c ? (-wt * sinf(ang) * INV256) : (wt * cosf(ang) * INV256);
        tw2[49152 + u] = bf16_rtn(v);
    }
}

// ---------------- Kernel 1: forward partial rfft2 via MFMA ----------------
__global__ __launch_bounds__(256) void fwd_mfma(const float* __restrict__ x,
                                                const u16* __restrict__ tw,
                                                float2* __restrict__ xft) {
    __shared__ u16 planes[4 * 32 * 264];   // 67584 B
    const int t = threadIdx.x;
    const int lane = t & 63;
    const int wv = t >> 6;
    const int l15 = lane & 15;
    const int lk = lane >> 4;
    const float* __restrict__ xb = x + (size_t)blockIdx.x * (NH * NW);

    const u16* __restrict__ T1h = tw;
    const u16* __restrict__ T1l = tw + 16384;

    for (int mt = 0; mt < 4; ++mt) {
        const int hbase = wv * 64 + mt * 16;
        f32x4 acc[4] = {f32x4{0,0,0,0}, f32x4{0,0,0,0}, f32x4{0,0,0,0}, f32x4{0,0,0,0}};
        for (int kc = 0; kc < 8; ++kc) {
            const float* xr = xb + (size_t)(hbase + l15) * NW + kc * 32 + lk * 8;
            const float4 xa = *(const float4*)xr;
            const float4 xc = *(const float4*)(xr + 4);
            const float v[8] = {xa.x, xa.y, xa.z, xa.w, xc.x, xc.y, xc.z, xc.w};
            short8v Ah, Al;
            #pragma unroll
            for (int e = 0; e < 8; ++e) {
                u16 hi, lo; bf16_split(v[e], hi, lo);
                Ah[e] = (short)hi; Al[e] = (short)lo;
            }
            const int tbase = (kc * 4) * 512 + lane * 8;
            #pragma unroll
            for (int nt = 0; nt < 4; ++nt) {
                const short8v Bh = *(const short8v*)(T1h + tbase + nt * 512);
                const short8v Bl = *(const short8v*)(T1l + tbase + nt * 512);
                acc[nt] = __builtin_amdgcn_mfma_f32_16x16x32_bf16(Ah, Bh, acc[nt], 0, 0, 0);
                acc[nt] = __builtin_amdgcn_mfma_f32_16x16x32_bf16(Ah, Bl, acc[nt], 0, 0, 0);
                acc[nt] = __builtin_amdgcn_mfma_f32_16x16x32_bf16(Al, Bh, acc[nt], 0, 0, 0);
            }
        }
        #pragma unroll
        for (int nt = 0; nt < 4; ++nt) {
            const int n = nt * 16 + l15;
            const int kx = n >> 1, p = n & 1;
            #pragma unroll
            for (int r = 0; r < 4; ++r) {
                const int h = hbase + lk * 4 + r;
                u16 hi, lo; bf16_split(acc[nt][r], hi, lo);
                planes[(2 * p) * 8448 + kx * 264 + h] = hi;
                planes[(2 * p + 1) * 8448 + kx * 264 + h] = lo;
            }
        }
    }
    __syncthreads();

    const u16* __restrict__ C2h = tw + 32768;
    const u16* __restrict__ C2l = tw + 49152;
    const u16* __restrict__ S2h = tw + 65536;
    const u16* __restrict__ S2l = tw + 81920;
    const u16* __restrict__ Snh = tw + 98304;
    const u16* __restrict__ Snl = tw + 114688;

    f32x4 zre[2] = {f32x4{0,0,0,0}, f32x4{0,0,0,0}};
    f32x4 zim[2] = {f32x4{0,0,0,0}, f32x4{0,0,0,0}};
    for (int kc = 0; kc < 8; ++kc) {
        const int abase = (wv * 8 + kc) * 512 + lane * 8;
        const short8v Ch = *(const short8v*)(C2h + abase);
        const short8v Cl = *(const short8v*)(C2l + abase);
        const short8v Sh = *(const short8v*)(S2h + abase);
        const short8v Sl = *(const short8v*)(S2l + abase);
        const short8v Nh = *(const short8v*)(Snh + abase);
        const short8v Nl = *(const short8v*)(Snl + abase);
        #pragma unroll
        for (int nt = 0; nt < 2; ++nt) {
            const int kx = nt * 16 + l15;
            const int off = kx * 264 + kc * 32 + lk * 8;
            const short8v Yrh = *(const short8v*)(planes + off);
            const short8v Yrl = *(const short8v*)(planes + 8448 + off);
            const short8v Yih = *(const short8v*)(planes + 16896 + off);
            const short8v Yil = *(const short8v*)(planes + 25344 + off);
            zre[nt] = __builtin_amdgcn_mfma_f32_16x16x32_bf16(Ch, Yrh, zre[nt], 0, 0, 0);
            zre[nt] = __builtin_amdgcn_mfma_f32_16x16x32_bf16(Ch, Yrl, zre[nt], 0, 0, 0);
            zre[nt] = __builtin_amdgcn_mfma_f32_16x16x32_bf16(Cl, Yrh, zre[nt], 0, 0, 0);
            zre[nt] = __builtin_amdgcn_mfma_f32_16x16x32_bf16(Sh, Yih, zre[nt], 0, 0, 0);
            zre[nt] = __builtin_amdgcn_mfma_f32_16x16x32_bf16(Sh, Yil, zre[nt], 0, 0, 0);
            zre[nt] = __builtin_amdgcn_mfma_f32_16x16x32_bf16(Sl, Yih, zre[nt], 0, 0, 0);
            zim[nt] = __builtin_amdgcn_mfma_f32_16x16x32_bf16(Ch, Yih, zim[nt], 0, 0, 0);
            zim[nt] = __builtin_amdgcn_mfma_f32_16x16x32_bf16(Ch, Yil, zim[nt], 0, 0, 0);
            zim[nt] = __builtin_amdgcn_mfma_f32_16x16x32_bf16(Cl, Yih, zim[nt], 0, 0, 0);
            zim[nt] = __builtin_amdgcn_mfma_f32_16x16x32_bf16(Nh, Yrh, zim[nt], 0, 0, 0);
            zim[nt] = __builtin_amdgcn_mfma_f32_16x16x32_bf16(Nh, Yrl, zim[nt], 0, 0, 0);
            zim[nt] = __builtin_amdgcn_mfma_f32_16x16x32_bf16(Nl, Yrh, zim[nt], 0, 0, 0);
        }
    }
    float2* __restrict__ op = xft + (size_t)blockIdx.x * (NM * NKX);
    #pragma unroll
    for (int nt = 0; nt < 2; ++nt) {
        const int kx = nt * 16 + l15;
        #pragma unroll
        for (int r = 0; r < 4; ++r) {
            const int m = wv * 16 + lk * 4 + r;
            op[m * NKX + kx] = make_float2(zre[nt][r] * INV256, zim[nt][r] * INV256);
        }
    }
}

// ---------------- Kernel 2: per-mode channel contraction (v2) ----------------
// grid = (m=64, og=4, kh=4), 256 threads. Latency-hiding pipeline:
// issue loads(i+1) -> compute(i) from LDS[cur] -> dequant+write LDS[cur^1] -> barrier.
// Thread (b = t>>4, o = t&15) accumulates 8 kx complex outputs.
// Loader split is wave-uniform: waves 0-1 load x, waves 2-3 load weights.
__global__ __launch_bounds__(256) void mode_v2(const float2* __restrict__ xft,
                                               const int* __restrict__ q1,
                                               const int* __restrict__ q2,
                                               const float* __restrict__ w1s,
                                               const float* __restrict__ w1m,
                                               const float* __restrict__ w2s,
                                               const float* __restrict__ w2m,
                                               float2* __restrict__ oft) {
    __shared__ float2 xs[2][16][8];     // [buf][b][kx] — reads are 16-way broadcast
    __shared__ float2 ws[2][16][9];     // [buf][o][kx] pad-9 -> conflict-free reads
    const int m  = blockIdx.x;          // 0..63
    const int og = blockIdx.y;          // 0..3
    const int kh = blockIdx.z;          // 0..3
    const int t = threadIdx.x;
    const int b = t >> 4, o = t & 15;
    const int mm = (m < 32) ? m : (m - 32);
    const int2* __restrict__ qp = (const int2*)((m < 32) ? q1 : q2);
    const float scale = (m < 32) ? w1s[0] : w2s[0];
    const float wmin  = (m < 32) ? w1m[0] : w2m[0];

    const bool isx = t < 128;           // wave-uniform
    const int r8 = (t & 127) >> 3;      // 0..15 (row: b for x-loaders, o for w-loaders)
    const int k8 = t & 7;               // 0..7  (kx within this kh group)

    const float2* __restrict__ xsrc = xft + (size_t)(r8 * 64) * (NM * NKX)
                                          + m * NKX + kh * 8 + k8;          // += 2048/i
    const int2* __restrict__ wsrc = qp + (size_t)(og * 16 + r8) * 1024
                                       + mm * 32 + kh * 8 + k8;             // += 65536/i

    float2 px; int2 pw;
    if (isx) px = xsrc[0]; else pw = wsrc[0];
    if (isx) xs[0][r8][k8] = px;
    else     ws[0][r8][k8] = make_float2(((float)pw.x + 127.0f) * scale + wmin,
                                         ((float)pw.y + 127.0f) * scale + wmin);
    __syncthreads();

    float accr[8], acci[8];
    #pragma unroll
    for (int k = 0; k < 8; ++k) { accr[k] = 0.f; acci[k] = 0.f; }

    for (int i = 0; i < 64; ++i) {
        const int cur = i & 1;
        if (i < 63) {                   // issue prefetch for i+1
            if (isx) px = xsrc[(size_t)(i + 1) * (NM * NKX)];
            else     pw = wsrc[(size_t)(i + 1) * 65536];
        }
        #pragma unroll
        for (int k = 0; k < 8; ++k) {
            const float2 xv = xs[cur][b][k];
            const float2 wv = ws[cur][o][k];
            accr[k] += xv.x * wv.x - xv.y * wv.y;
            acci[k] += xv.x * wv.y + xv.y * wv.x;
        }
        if (i < 63) {
            if (isx) xs[cur ^ 1][r8][k8] = px;
            else     ws[cur ^ 1][r8][k8] = make_float2(((float)pw.x + 127.0f) * scale + wmin,
                                                       ((float)pw.y + 127.0f) * scale + wmin);
            __syncthreads();
        }
    }

    float2* __restrict__ op = oft + ((size_t)(b * 64 + og * 16 + o) * NM + m) * NKX + kh * 8;
    #pragma unroll
    for (int k = 0; k < 8; ++k) op[k] = make_float2(accr[k], acci[k]);
}

// ---------------- Kernel 3: inverse partial irfft2 via MFMA ----------------
__global__ __launch_bounds__(256) void inv_mfma(const float2* __restrict__ oft,
                                                const u16* __restrict__ tw2,
                                                float* __restrict__ out) {
    __shared__ u16 lds[23040];   // 46080 B
    const int t = threadIdx.x;
    const int lane = t & 63;
    const int wv = t >> 6;
    const int l15 = lane & 15;
    const int lk = lane >> 4;

    const float2* __restrict__ ip = oft + (size_t)blockIdx.x * (NM * NKX);
    #pragma unroll
    for (int r = 0; r < 8; ++r) {
        const int idx = r * 256 + t;
        const int m = idx >> 5, kx = idx & 31;
        const float2 v = ip[idx];
        lds[kx * 72 + m]        = bf16_rtn(v.x);
        lds[2304 + kx * 72 + m] = bf16_rtn(v.y);
    }
    __syncthreads();

    const u16* __restrict__ C4 = tw2;
    const u16* __restrict__ S4 = tw2 + 16384;
    const u16* __restrict__ N4 = tw2 + 32768;

    short8v Br[2][2], Bi[2][2];
    #pragma unroll
    for (int nt = 0; nt < 2; ++nt) {
        #pragma unroll
        for (int kc = 0; kc < 2; ++kc) {
            const int off = (nt * 16 + l15) * 72 + kc * 32 + lk * 8;
            Br[nt][kc] = *(const short8v*)(lds + off);
            Bi[nt][kc] = *(const short8v*)(lds + 2304 + off);
        }
    }

    for (int mt = 0; mt < 4; ++mt) {
        const int HT = wv * 4 + mt;
        f32x4 zr[2] = {f32x4{0,0,0,0}, f32x4{0,0,0,0}};
        f32x4 zi[2] = {f32x4{0,0,0,0}, f32x4{0,0,0,0}};
        #pragma unroll
        for (int kc = 0; kc < 2; ++kc) {
            const int abase = ((HT * 2 + kc) * 64 + lane) * 8;
            const short8v C = *(const short8v*)(C4 + abase);
            const short8v S = *(const short8v*)(S4 + abase);
            const short8v N = *(const short8v*)(N4 + abase);
            #pragma unroll
            for (int nt = 0; nt < 2; ++nt) {
                zr[nt] = __builtin_amdgcn_mfma_f32_16x16x32_bf16(C, Br[nt][kc], zr[nt], 0, 0, 0);
                zr[nt] = __builtin_amdgcn_mfma_f32_16x16x32_bf16(N, Bi[nt][kc], zr[nt], 0, 0, 0);
                zi[nt] = __builtin_amdgcn_mfma_f32_16x16x32_bf16(S, Br[nt][kc], zi[nt], 0, 0, 0);
                zi[nt] = __builtin_amdgcn_mfma_f32_16x16x32_bf16(C, Bi[nt][kc], zi[nt], 0, 0, 0);
            }
        }
        #pragma unroll
        for (int nt = 0; nt < 2; ++nt) {
            const int kx = nt * 16 + l15;
            #pragma unroll
            for (int r = 0; r < 4; ++r) {
                const int h = HT * 16 + lk * 4 + r;
                const u32 pk = (u32)bf16_rtn(zr[nt][r]) | ((u32)bf16_rtn(zi[nt][r]) << 16);
                *(u32*)(lds + 4608 + h * 72 + 2 * kx) = pk;
            }
        }
    }
    __syncthreads();

    const u16* __restrict__ W5 = tw2 + 49152;
    float* __restrict__ op = out + (size_t)blockIdx.x * (NH * NW);
    for (int nt = 0; nt < 16; ++nt) {
        const short8v B0 = *(const short8v*)(W5 + ((nt * 2 + 0) * 64 + lane) * 8);
        const short8v B1 = *(const short8v*)(W5 + ((nt * 2 + 1) * 64 + lane) * 8);
        const int w = nt * 16 + l15;
        #pragma unroll
        for (int mt = 0; mt < 4; ++mt) {
            const int HT = wv * 4 + mt;
            const int h0 = HT * 16 + l15;
            const short8v A0 = *(const short8v*)(lds + 4608 + h0 * 72 + lk * 8);
            const short8v A1 = *(const short8v*)(lds + 4608 + h0 * 72 + 32 + lk * 8);
            f32x4 acc = {0, 0, 0, 0};
            acc = __builtin_amdgcn_mfma_f32_16x16x32_bf16(A0, B0, acc, 0, 0, 0);
            acc = __builtin_amdgcn_mfma_f32_16x16x32_bf16(A1, B1, acc, 0, 0, 0);
            #pragma unroll
            for (int r = 0; r < 4; ++r) {
                const int h = HT * 16 + lk * 4 + r;
                op[h * 256 + w] = acc[r];
            }
        }
    }
}

extern "C" void kernel_launch(void* const* d_in, const int* in_sizes, int n_in,
                              void* d_out, int out_size, void* d_ws, size_t ws_size,
                              hipStream_t stream) {
    const float* x  = (const float*)d_in[0];
    const int* q1   = (const int*)d_in[1];
    const int* q2   = (const int*)d_in[2];
    const float* w1s = (const float*)d_in[3];
    const float* w1m = (const float*)d_in[4];
    const float* w2s = (const float*)d_in[5];
    const float* w2m = (const float*)d_in[6];
    float* out = (float*)d_out;

    float2* xft = (float2*)d_ws;                          // 16 MiB
    float2* oft = xft + (size_t)NB * NCIN * NM * NKX;     // +16 MiB
    u16* tw  = (u16*)oft;   // fwd tables: head of oft region, clobbered by mode
    u16* tw2 = (u16*)xft;   // inv tables: head of xft region, written after mode

    init_tw<<<128, 256, 0, stream>>>(tw);
    fwd_mfma<<<NB * NCIN, 256, 0, stream>>>(x, tw, xft);
    mode_v2<<<dim3(NM, 4, 4), 256, 0, stream>>>(xft, q1, q2, w1s, w1m, w2s, w2m, oft);
    init_tw2<<<128, 256, 0, stream>>>(tw2);
    inv_mfma<<<NB * NCOUT, 256, 0, stream>>>(oft, tw2, out);
}

// Round 5
// 220.426 us; speedup vs baseline: 4.2781x; 1.0147x over previous
//
#include <hip/hip_runtime.h>
#include <math.h>

#define NB 16
#define NCIN 64
#define NCOUT 64
#define NH 256
#define NW 256
#define NM 64          // 2*M1 row modes
#define NKX 32         // M2 retained columns
#define INV256 (1.0f/256.0f)

typedef __attribute__((ext_vector_type(8))) short short8v;
typedef __attribute__((ext_vector_type(4))) float f32x4;
typedef unsigned short u16;
typedef unsigned int u32;

__device__ __forceinline__ void bf16_split(float v, u16& hi, u16& lo) {
    u32 b = __float_as_uint(v);
    u32 hib = b & 0xffff0000u;
    float lof = v - __uint_as_float(hib);
    hi = (u16)(hib >> 16);
    lo = (u16)(__float_as_uint(lof) >> 16);
}

__device__ __forceinline__ u16 bf16_rtn(float v) {
    u32 b = __float_as_uint(v);
    u32 r = b + 0x7fffu + ((b >> 16) & 1u);
    return (u16)(r >> 16);
}

// ---------------- fwd twiddle tables (at head of oft region) ----------------
//  T1h @ 0      T1l @ 16384   : [kc 8][nt 4][lane 64][e 8]  (phase-1 B frags)
//  C2h @ 32768  C2l @ 49152   : [mt 4][kc 8][lane 64][e 8]  (phase-2 A frags)
//  S2h @ 65536  S2l @ 81920
//  Snh @ 98304  Snl @ 114688
__global__ __launch_bounds__(256) void init_tw(u16* __restrict__ tw) {
    const int tid = blockIdx.x * 256 + threadIdx.x;   // 0..32767
    const float TWO_PI = 6.28318530717958647692f;
    if (tid < 16384) {
        const int e = tid & 7, lane = (tid >> 3) & 63;
        const int nt = (tid >> 9) & 3, kc = tid >> 11;
        const int w = kc * 32 + (lane >> 4) * 8 + e;
        const int n = nt * 16 + (lane & 15);
        const int kx = n >> 1, p = n & 1;
        const float ang = TWO_PI * (float)((kx * w) & 255) * INV256;
        const float v = p ? -sinf(ang) : cosf(ang);
        u16 hi, lo; bf16_split(v, hi, lo);
        tw[tid] = hi; tw[16384 + tid] = lo;
    } else {
        const int u = tid - 16384;
        const int e = u & 7, lane = (u >> 3) & 63;
        const int kc = (u >> 9) & 7, mt = u >> 12;
        const int m = mt * 16 + (lane & 15);
        const int h = kc * 32 + (lane >> 4) * 8 + e;
        const int ky = (m < 32) ? m : (192 + m);
        const float ang = TWO_PI * (float)((ky * h) & 255) * INV256;
        const float c = cosf(ang), s = sinf(ang);
        u16 hi, lo;
        bf16_split(c,  hi, lo); tw[32768 + u] = hi; tw[49152 + u]  = lo;
        bf16_split(s,  hi, lo); tw[65536 + u] = hi; tw[81920 + u]  = lo;
        bf16_split(-s, hi, lo); tw[98304 + u] = hi; tw[114688 + u] = lo;
    }
}

// ---------------- inv twiddle tables (written into dead xft region) ---------
//  C4 @ 0      S4 @ 16384    N4 @ 32768 : [HT 16][kc 2][lane 64][e 8]
//  W5 @ 49152                           : [nt 16][kc 2][lane 64][e 8]
//  W5 k-order interleaved: kk = 2*kx + c; c=0 -> wt*cos/256, c=1 -> -wt*sin/256
__global__ __launch_bounds__(256) void init_tw2(u16* __restrict__ tw2) {
    const int tid = blockIdx.x * 256 + threadIdx.x;   // 0..32767
    const float TWO_PI = 6.28318530717958647692f;
    if (tid < 16384) {
        const int e = tid & 7, lane = (tid >> 3) & 63;
        const int kc = (tid >> 9) & 1, HT = tid >> 10;
        const int h = HT * 16 + (lane & 15);
        const int m = kc * 32 + ((lane >> 4) << 3) + e;
        const int ky = (m < 32) ? m : (192 + m);
        const float ang = TWO_PI * (float)((ky * h) & 255) * INV256;
        tw2[tid]         = bf16_rtn(cosf(ang));
        tw2[16384 + tid] = bf16_rtn(sinf(ang));
        tw2[32768 + tid] = bf16_rtn(-sinf(ang));
    } else {
        const int u = tid - 16384;
        const int e = u & 7, lane = (u >> 3) & 63;
        const int kc = (u >> 9) & 1, nt = u >> 10;
        const int w = nt * 16 + (lane & 15);
        const int kk = kc * 32 + ((lane >> 4) << 3) + e;
        const int kx = kk >> 1, c = kk & 1;
        const float wt = (kx == 0) ? 1.f : 2.f;
        const float ang = TWO_PI * (float)((kx * w) & 255) * INV256;
        const float v = c ? (-wt * sinf(ang) * INV256) : (wt * cosf(ang) * INV256);
        tw2[49152 + u] = bf16_rtn(v);
    }
}

// ---------------- Kernel 1: forward partial rfft2 via MFMA ----------------
__global__ __launch_bounds__(256) void fwd_mfma(const float* __restrict__ x,
                                                const u16* __restrict__ tw,
                                                float2* __restrict__ xft) {
    __shared__ u16 planes[4 * 32 * 264];   // 67584 B
    const int t = threadIdx.x;
    const int lane = t & 63;
    const int wv = t >> 6;
    const int l15 = lane & 15;
    const int lk = lane >> 4;
    const float* __restrict__ xb = x + (size_t)blockIdx.x * (NH * NW);

    const u16* __restrict__ T1h = tw;
    const u16* __restrict__ T1l = tw + 16384;

    for (int mt = 0; mt < 4; ++mt) {
        const int hbase = wv * 64 + mt * 16;
        f32x4 acc[4] = {f32x4{0,0,0,0}, f32x4{0,0,0,0}, f32x4{0,0,0,0}, f32x4{0,0,0,0}};
        for (int kc = 0; kc < 8; ++kc) {
            const float* xr = xb + (size_t)(hbase + l15) * NW + kc * 32 + lk * 8;
            const float4 xa = *(const float4*)xr;
            const float4 xc = *(const float4*)(xr + 4);
            const float v[8] = {xa.x, xa.y, xa.z, xa.w, xc.x, xc.y, xc.z, xc.w};
            short8v Ah, Al;
            #pragma unroll
            for (int e = 0; e < 8; ++e) {
                u16 hi, lo; bf16_split(v[e], hi, lo);
                Ah[e] = (short)hi; Al[e] = (short)lo;
            }
            const int tbase = (kc * 4) * 512 + lane * 8;
            #pragma unroll
            for (int nt = 0; nt < 4; ++nt) {
                const short8v Bh = *(const short8v*)(T1h + tbase + nt * 512);
                const short8v Bl = *(const short8v*)(T1l + tbase + nt * 512);
                acc[nt] = __builtin_amdgcn_mfma_f32_16x16x32_bf16(Ah, Bh, acc[nt], 0, 0, 0);
                acc[nt] = __builtin_amdgcn_mfma_f32_16x16x32_bf16(Ah, Bl, acc[nt], 0, 0, 0);
                acc[nt] = __builtin_amdgcn_mfma_f32_16x16x32_bf16(Al, Bh, acc[nt], 0, 0, 0);
            }
        }
        #pragma unroll
        for (int nt = 0; nt < 4; ++nt) {
            const int n = nt * 16 + l15;
            const int kx = n >> 1, p = n & 1;
            #pragma unroll
            for (int r = 0; r < 4; ++r) {
                const int h = hbase + lk * 4 + r;
                u16 hi, lo; bf16_split(acc[nt][r], hi, lo);
                planes[(2 * p) * 8448 + kx * 264 + h] = hi;
                planes[(2 * p + 1) * 8448 + kx * 264 + h] = lo;
            }
        }
    }
    __syncthreads();

    const u16* __restrict__ C2h = tw + 32768;
    const u16* __restrict__ C2l = tw + 49152;
    const u16* __restrict__ S2h = tw + 65536;
    const u16* __restrict__ S2l = tw + 81920;
    const u16* __restrict__ Snh = tw + 98304;
    const u16* __restrict__ Snl = tw + 114688;

    f32x4 zre[2] = {f32x4{0,0,0,0}, f32x4{0,0,0,0}};
    f32x4 zim[2] = {f32x4{0,0,0,0}, f32x4{0,0,0,0}};
    for (int kc = 0; kc < 8; ++kc) {
        const int abase = (wv * 8 + kc) * 512 + lane * 8;
        const short8v Ch = *(const short8v*)(C2h + abase);
        const short8v Cl = *(const short8v*)(C2l + abase);
        const short8v Sh = *(const short8v*)(S2h + abase);
        const short8v Sl = *(const short8v*)(S2l + abase);
        const short8v Nh = *(const short8v*)(Snh + abase);
        const short8v Nl = *(const short8v*)(Snl + abase);
        #pragma unroll
        for (int nt = 0; nt < 2; ++nt) {
            const int kx = nt * 16 + l15;
            const int off = kx * 264 + kc * 32 + lk * 8;
            const short8v Yrh = *(const short8v*)(planes + off);
            const short8v Yrl = *(const short8v*)(planes + 8448 + off);
            const short8v Yih = *(const short8v*)(planes + 16896 + off);
            const short8v Yil = *(const short8v*)(planes + 25344 + off);
            zre[nt] = __builtin_amdgcn_mfma_f32_16x16x32_bf16(Ch, Yrh, zre[nt], 0, 0, 0);
            zre[nt] = __builtin_amdgcn_mfma_f32_16x16x32_bf16(Ch, Yrl, zre[nt], 0, 0, 0);
            zre[nt] = __builtin_amdgcn_mfma_f32_16x16x32_bf16(Cl, Yrh, zre[nt], 0, 0, 0);
            zre[nt] = __builtin_amdgcn_mfma_f32_16x16x32_bf16(Sh, Yih, zre[nt], 0, 0, 0);
            zre[nt] = __builtin_amdgcn_mfma_f32_16x16x32_bf16(Sh, Yil, zre[nt], 0, 0, 0);
            zre[nt] = __builtin_amdgcn_mfma_f32_16x16x32_bf16(Sl, Yih, zre[nt], 0, 0, 0);
            zim[nt] = __builtin_amdgcn_mfma_f32_16x16x32_bf16(Ch, Yih, zim[nt], 0, 0, 0);
            zim[nt] = __builtin_amdgcn_mfma_f32_16x16x32_bf16(Ch, Yil, zim[nt], 0, 0, 0);
            zim[nt] = __builtin_amdgcn_mfma_f32_16x16x32_bf16(Cl, Yih, zim[nt], 0, 0, 0);
            zim[nt] = __builtin_amdgcn_mfma_f32_16x16x32_bf16(Nh, Yrh, zim[nt], 0, 0, 0);
            zim[nt] = __builtin_amdgcn_mfma_f32_16x16x32_bf16(Nh, Yrl, zim[nt], 0, 0, 0);
            zim[nt] = __builtin_amdgcn_mfma_f32_16x16x32_bf16(Nl, Yrh, zim[nt], 0, 0, 0);
        }
    }
    float2* __restrict__ op = xft + (size_t)blockIdx.x * (NM * NKX);
    #pragma unroll
    for (int nt = 0; nt < 2; ++nt) {
        const int kx = nt * 16 + l15;
        #pragma unroll
        for (int r = 0; r < 4; ++r) {
            const int m = wv * 16 + lk * 4 + r;
            op[m * NKX + kx] = make_float2(zre[nt][r] * INV256, zim[nt][r] * INV256);
        }
    }
}

// ---------------- Kernel 2: per-mode channel contraction (v3) ----------------
// grid = (m=64, og=4, kh=4), 256 threads. Depth-2 register prefetch:
// at iter i: compute(i from LDS) -> write reg(i+1) -> barrier -> issue load(i+3).
// pa holds even-indexed data, pb odd-indexed (static reg slots, i-loop unrolled x2).
__global__ __launch_bounds__(256) void mode_v3(const float2* __restrict__ xft,
                                               const int* __restrict__ q1,
                                               const int* __restrict__ q2,
                                               const float* __restrict__ w1s,
                                               const float* __restrict__ w1m,
                                               const float* __restrict__ w2s,
                                               const float* __restrict__ w2m,
                                               float2* __restrict__ oft) {
    __shared__ float2 xs[2][16][8];     // [buf][b][kx] — reads are 16-way broadcast
    __shared__ float2 ws[2][16][9];     // [buf][o][kx] pad-9 -> conflict-free reads
    const int m  = blockIdx.x;          // 0..63
    const int og = blockIdx.y;          // 0..3
    const int kh = blockIdx.z;          // 0..3
    const int t = threadIdx.x;
    const int b = t >> 4, o = t & 15;
    const int mm = (m < 32) ? m : (m - 32);
    const int2* __restrict__ qp = (const int2*)((m < 32) ? q1 : q2);
    const float scale = (m < 32) ? w1s[0] : w2s[0];
    const float wmin  = (m < 32) ? w1m[0] : w2m[0];

    const bool isx = t < 128;           // wave-uniform
    const int r8 = (t & 127) >> 3;      // 0..15 (row: b for x-loaders, o for w-loaders)
    const int k8 = t & 7;               // 0..7  (kx within this kh group)

    const float2* __restrict__ xsrc = xft + (size_t)(r8 * 64) * (NM * NKX)
                                          + m * NKX + kh * 8 + k8;          // += 2048/i
    const int2* __restrict__ wsrc = qp + (size_t)(og * 16 + r8) * 1024
                                       + mm * 32 + kh * 8 + k8;             // += 65536/i

    // prologue: data0 -> LDS[0]; pb <- data1; pa <- data2
    float2 pxa, pxb; int2 pwa, pwb;
    if (isx) {
        const float2 p0 = xsrc[0];
        xs[0][r8][k8] = p0;
        pxb = xsrc[(size_t)1 * (NM * NKX)];
        pxa = xsrc[(size_t)2 * (NM * NKX)];
    } else {
        const int2 p0 = wsrc[0];
        ws[0][r8][k8] = make_float2(((float)p0.x + 127.0f) * scale + wmin,
                                    ((float)p0.y + 127.0f) * scale + wmin);
        pwb = wsrc[(size_t)1 * 65536];
        pwa = wsrc[(size_t)2 * 65536];
    }
    __syncthreads();

    float accr[8], acci[8];
    #pragma unroll
    for (int k = 0; k < 8; ++k) { accr[k] = 0.f; acci[k] = 0.f; }

    #pragma unroll 1
    for (int j = 0; j < 32; ++j) {
        const int i0 = 2 * j;           // even iter: compute LDS[0], write pb->LDS[1]
        #pragma unroll
        for (int k = 0; k < 8; ++k) {
            const float2 xv = xs[0][b][k];
            const float2 wv = ws[0][o][k];
            accr[k] += xv.x * wv.x - xv.y * wv.y;
            acci[k] += xv.x * wv.y + xv.y * wv.x;
        }
        {   // i0 <= 62 always (j<=31 -> i0<=62): write data(i0+1)
            if (isx) xs[1][r8][k8] = pxb;
            else     ws[1][r8][k8] = make_float2(((float)pwb.x + 127.0f) * scale + wmin,
                                                 ((float)pwb.y + 127.0f) * scale + wmin);
            __syncthreads();
            if (i0 + 3 < 64) {
                if (isx) pxb = xsrc[(size_t)(i0 + 3) * (NM * NKX)];
                else     pwb = wsrc[(size_t)(i0 + 3) * 65536];
            }
        }
        const int i1 = 2 * j + 1;       // odd iter: compute LDS[1], write pa->LDS[0]
        #pragma unroll
        for (int k = 0; k < 8; ++k) {
            const float2 xv = xs[1][b][k];
            const float2 wv = ws[1][o][k];
            accr[k] += xv.x * wv.x - xv.y * wv.y;
            acci[k] += xv.x * wv.y + xv.y * wv.x;
        }
        if (i1 < 63) {                  // write data(i1+1)
            if (isx) xs[0][r8][k8] = pxa;
            else     ws[0][r8][k8] = make_float2(((float)pwa.x + 127.0f) * scale + wmin,
                                                 ((float)pwa.y + 127.0f) * scale + wmin);
            __syncthreads();
            if (i1 + 3 < 64) {
                if (isx) pxa = xsrc[(size_t)(i1 + 3) * (NM * NKX)];
                else     pwa = wsrc[(size_t)(i1 + 3) * 65536];
            }
        }
    }

    float2* __restrict__ op = oft + ((size_t)(b * 64 + og * 16 + o) * NM + m) * NKX + kh * 8;
    #pragma unroll
    for (int k = 0; k < 8; ++k) op[k] = make_float2(accr[k], acci[k]);
}

// ---------------- Kernel 3: inverse partial irfft2 via MFMA (split-h) -------
// grid = (B*COUT, 2), 256 threads (4 waves). Block handles 128 h rows.
// Phase 4: Z[128h][32kx](re,im) = twiddle[h][m] x O[m][kx]   (K=64)
// Phase 5: out[128h][256w] = Zstack[128h][64kk] x W5[64kk][256w]
// LDS (ushort): OrP @0 [32kx][72], OiP @2304, Zp @4608 [128hl][72]
__global__ __launch_bounds__(256) void inv_mfma(const float2* __restrict__ oft,
                                                const u16* __restrict__ tw2,
                                                float* __restrict__ out) {
    __shared__ u16 lds[13824];   // 27648 B -> 5 blocks/CU
    const int t = threadIdx.x;
    const int lane = t & 63;
    const int wv = t >> 6;
    const int l15 = lane & 15;
    const int lk = lane >> 4;
    const int hh = blockIdx.y;   // 0/1: h half

    const float2* __restrict__ ip = oft + (size_t)blockIdx.x * (NM * NKX);
    #pragma unroll
    for (int r = 0; r < 8; ++r) {
        const int idx = r * 256 + t;
        const int m = idx >> 5, kx = idx & 31;
        const float2 v = ip[idx];
        lds[kx * 72 + m]        = bf16_rtn(v.x);
        lds[2304 + kx * 72 + m] = bf16_rtn(v.y);
    }
    __syncthreads();

    const u16* __restrict__ C4 = tw2;
    const u16* __restrict__ S4 = tw2 + 16384;
    const u16* __restrict__ N4 = tw2 + 32768;

    short8v Br[2][2], Bi[2][2];
    #pragma unroll
    for (int nt = 0; nt < 2; ++nt) {
        #pragma unroll
        for (int kc = 0; kc < 2; ++kc) {
            const int off = (nt * 16 + l15) * 72 + kc * 32 + lk * 8;
            Br[nt][kc] = *(const short8v*)(lds + off);
            Bi[nt][kc] = *(const short8v*)(lds + 2304 + off);
        }
    }

    #pragma unroll
    for (int mt = 0; mt < 2; ++mt) {
        const int lt = wv * 2 + mt;       // local 16-row tile 0..7
        const int HT = hh * 8 + lt;       // global tile 0..15
        f32x4 zr[2] = {f32x4{0,0,0,0}, f32x4{0,0,0,0}};
        f32x4 zi[2] = {f32x4{0,0,0,0}, f32x4{0,0,0,0}};
        #pragma unroll
        for (int kc = 0; kc < 2; ++kc) {
            const int abase = ((HT * 2 + kc) * 64 + lane) * 8;
            const short8v C = *(const short8v*)(C4 + abase);
            const short8v S = *(const short8v*)(S4 + abase);
            const short8v N = *(const short8v*)(N4 + abase);
            #pragma unroll
            for (int nt = 0; nt < 2; ++nt) {
                zr[nt] = __builtin_amdgcn_mfma_f32_16x16x32_bf16(C, Br[nt][kc], zr[nt], 0, 0, 0);
                zr[nt] = __builtin_amdgcn_mfma_f32_16x16x32_bf16(N, Bi[nt][kc], zr[nt], 0, 0, 0);
                zi[nt] = __builtin_amdgcn_mfma_f32_16x16x32_bf16(S, Br[nt][kc], zi[nt], 0, 0, 0);
                zi[nt] = __builtin_amdgcn_mfma_f32_16x16x32_bf16(C, Bi[nt][kc], zi[nt], 0, 0, 0);
            }
        }
        #pragma unroll
        for (int nt = 0; nt < 2; ++nt) {
            const int kx = nt * 16 + l15;
            #pragma unroll
            for (int r = 0; r < 4; ++r) {
                const int hl = lt * 16 + lk * 4 + r;
                const u32 pk = (u32)bf16_rtn(zr[nt][r]) | ((u32)bf16_rtn(zi[nt][r]) << 16);
                *(u32*)(lds + 4608 + hl * 72 + 2 * kx) = pk;
            }
        }
    }
    __syncthreads();

    const u16* __restrict__ W5 = tw2 + 49152;
    float* __restrict__ op = out + (size_t)blockIdx.x * (NH * NW) + hh * 128 * NW;
    for (int nt = 0; nt < 16; ++nt) {
        const short8v B0 = *(const short8v*)(W5 + ((nt * 2 + 0) * 64 + lane) * 8);
        const short8v B1 = *(const short8v*)(W5 + ((nt * 2 + 1) * 64 + lane) * 8);
        const int w = nt * 16 + l15;
        #pragma unroll
        for (int mt = 0; mt < 2; ++mt) {
            const int lt = wv * 2 + mt;
            const int h0 = lt * 16 + l15;
            const short8v A0 = *(const short8v*)(lds + 4608 + h0 * 72 + lk * 8);
            const short8v A1 = *(const short8v*)(lds + 4608 + h0 * 72 + 32 + lk * 8);
            f32x4 acc = {0, 0, 0, 0};
            acc = __builtin_amdgcn_mfma_f32_16x16x32_bf16(A0, B0, acc, 0, 0, 0);
            acc = __builtin_amdgcn_mfma_f32_16x16x32_bf16(A1, B1, acc, 0, 0, 0);
            #pragma unroll
            for (int r = 0; r < 4; ++r) {
                const int hl = lt * 16 + lk * 4 + r;
                op[hl * 256 + w] = acc[r];
            }
        }
    }
}

extern "C" void kernel_launch(void* const* d_in, const int* in_sizes, int n_in,
                              void* d_out, int out_size, void* d_ws, size_t ws_size,
                              hipStream_t stream) {
    const float* x  = (const float*)d_in[0];
    const int* q1   = (const int*)d_in[1];
    const int* q2   = (const int*)d_in[2];
    const float* w1s = (const float*)d_in[3];
    const float* w1m = (const float*)d_in[4];
    const float* w2s = (const float*)d_in[5];
    const float* w2m = (const float*)d_in[6];
    float* out = (float*)d_out;

    float2* xft = (float2*)d_ws;                          // 16 MiB
    float2* oft = xft + (size_t)NB * NCIN * NM * NKX;     // +16 MiB
    u16* tw  = (u16*)oft;   // fwd tables: head of oft region, clobbered by mode
    u16* tw2 = (u16*)xft;   // inv tables: head of xft region, written after mode

    init_tw<<<128, 256, 0, stream>>>(tw);
    fwd_mfma<<<NB * NCIN, 256, 0, stream>>>(x, tw, xft);
    mode_v3<<<dim3(NM, 4, 4), 256, 0, stream>>>(xft, q1, q2, w1s, w1m, w2s, w2m, oft);
    init_tw2<<<128, 256, 0, stream>>>(tw2);
    inv_mfma<<<dim3(NB * NCOUT, 2), 256, 0, stream>>>(oft, tw2, out);
}